// Round 2
// baseline (22884.309 us; speedup 1.0000x reference)
//
#include <hip/hip_runtime.h>

#define LEAKY(v) ((v) >= 0.f ? (v) : 0.01f * (v))
#define NWG 512

struct Params {
    const float *x;
    const float *w1x, *b1x, *w2x, *b2x, *w3x, *b3x, *w4x, *b4x;
    const float *w1e, *b1e, *w2e, *b2e, *w3e, *b3e, *w4e, *b4e;
    const float *w5, *b5, *w6, *b6, *w7, *b7, *w8, *b8, *w9, *b9;
    float *ebuf, *tA, *tB, *p0, *p1, *preds, *out;
    unsigned *bar;   // bar[0]=cnt, bar[64]=gen (separate cache lines)
};

// Sense-reversing grid barrier. Requires all NWG workgroups co-resident
// (guaranteed: __launch_bounds__(256,2) => >=2 blocks/CU * 256 CUs = 512).
// Agent-scope atomics + threadfence handle non-coherent per-XCD L2s.
__device__ inline void gridbar(unsigned* cnt, unsigned* gen)
{
    __syncthreads();
    if (threadIdx.x == 0) {
        unsigned g = __hip_atomic_load(gen, __ATOMIC_RELAXED, __HIP_MEMORY_SCOPE_AGENT);
        __threadfence();  // release our wg's writes (device scope)
        unsigned v = __hip_atomic_fetch_add(cnt, 1u, __ATOMIC_ACQ_REL, __HIP_MEMORY_SCOPE_AGENT);
        if (v == NWG - 1) {
            __hip_atomic_store(cnt, 0u, __ATOMIC_RELAXED, __HIP_MEMORY_SCOPE_AGENT);
            __hip_atomic_store(gen, g + 1u, __ATOMIC_RELEASE, __HIP_MEMORY_SCOPE_AGENT);
        } else {
            while (__hip_atomic_load(gen, __ATOMIC_ACQUIRE, __HIP_MEMORY_SCOPE_AGENT) == g)
                __builtin_amdgcn_s_sleep(2);
        }
        __threadfence();  // acquire other wgs' writes
    }
    __syncthreads();
}

// Direct 3x3 conv, NCHW, W=256, width-pad 1, height-pad PH.
// Work unit = (z, cout_group of 4, output row); thread = output column.
__device__ void convL(const float* __restrict__ in, int inChS, int inRow0, int Hin, int inZS,
                      const float* __restrict__ w0, const float* __restrict__ b0,
                      const float* __restrict__ w1, const float* __restrict__ b1,
                      float* __restrict__ out, int outZS, int Hout, int CIN, int PH,
                      int NZ, int wg)
{
    const int wcol = threadIdx.x;
    const int units = NZ * 16 * Hout;
    for (int u = wg; u < units; u += NWG) {
        const int h  = u % Hout;
        const int cg = (u / Hout) & 15;
        const int z  = u / (16 * Hout);
        const float* W  = z ? w1 : w0;
        const float* Bv = z ? b1 : b0;
        const float* inp = in + (size_t)z * inZS;
        float* o = out + (size_t)z * outZS;
        const int coutBase = cg * 4;
        const int wstride = CIN * 9;

        float a0 = Bv[coutBase + 0];
        float a1 = Bv[coutBase + 1];
        float a2 = Bv[coutBase + 2];
        float a3 = Bv[coutBase + 3];

        for (int cin = 0; cin < CIN; ++cin) {
            const float* ib = inp + cin * inChS + (inRow0 + h - PH) * 256;
            const float* wb = W + coutBase * wstride + cin * 9;
            #pragma unroll
            for (int kh = 0; kh < 3; ++kh) {
                const int r = h + kh - PH;
                float vm = 0.f, v0 = 0.f, vp = 0.f;
                if (PH == 0 || (r >= 0 && r < Hin)) {
                    const float* row = ib + kh * 256;
                    vm = (wcol > 0)   ? row[wcol - 1] : 0.f;
                    v0 = row[wcol];
                    vp = (wcol < 255) ? row[wcol + 1] : 0.f;
                }
                const float* wk = wb + kh * 3;
                a0 += vm * wk[0]               + v0 * wk[1]               + vp * wk[2];
                a1 += vm * wk[wstride + 0]     + v0 * wk[wstride + 1]     + vp * wk[wstride + 2];
                a2 += vm * wk[2 * wstride + 0] + v0 * wk[2 * wstride + 1] + vp * wk[2 * wstride + 2];
                a3 += vm * wk[3 * wstride + 0] + v0 * wk[3 * wstride + 1] + vp * wk[3 * wstride + 2];
            }
        }

        const int ohw = Hout * 256;
        o[(coutBase + 0) * ohw + h * 256 + wcol] = LEAKY(a0);
        o[(coutBase + 1) * ohw + h * 256 + wcol] = LEAKY(a1);
        o[(coutBase + 2) * ohw + h * 256 + wcol] = LEAKY(a2);
        o[(coutBase + 3) * ohw + h * 256 + wcol] = LEAKY(a3);
    }
}

// Per-pixel 8x8 @ 8x8: pr[8i+k] = sum_j e[8i+j] * s[8j+k]
// Register-lean version: sv[64] + ev[8] + acc (fits 128-VGPR bound).
__device__ void mm88d(const float* __restrict__ tw, float* __restrict__ p0, int wg)
{
    for (int u = wg; u < 9; u += NWG) {
        const int idx = u * 256 + threadIdx.x;
        const float* s = tw;
        const float* e = tw + 64 * 9 * 256;
        float sv[64];
        #pragma unroll
        for (int c = 0; c < 64; ++c) sv[c] = s[c * 9 * 256 + idx];
        #pragma unroll
        for (int i = 0; i < 8; ++i) {
            float ev[8];
            #pragma unroll
            for (int j = 0; j < 8; ++j) ev[j] = e[(i * 8 + j) * 9 * 256 + idx];
            #pragma unroll
            for (int k = 0; k < 8; ++k) {
                float acc = 0.f;
                #pragma unroll
                for (int j = 0; j < 8; ++j) acc += ev[j] * sv[j * 8 + k];
                p0[(i * 8 + k) * 9 * 256 + idx] = acc;
            }
        }
    }
}

// conv9 (64->3, ph=1 on H=1 -> only kh=1 taps), leaky, pred store,
// ebuf[i+15] = x[i+15] - pr.  Single workgroup.
__device__ void conv9upd(const float* __restrict__ pin, const float* __restrict__ w9,
                         const float* __restrict__ b9, const float* __restrict__ x,
                         float* __restrict__ ebuf, float* __restrict__ preds, int i)
{
    const int wcol = threadIdx.x;
    float acc0 = b9[0], acc1 = b9[1], acc2 = b9[2];
    for (int cin = 0; cin < 64; ++cin) {
        const float* row = pin + cin * 256;
        float vm = (wcol > 0)   ? row[wcol - 1] : 0.f;
        float v0 = row[wcol];
        float vp = (wcol < 255) ? row[wcol + 1] : 0.f;
        const float* wk0 = w9 + (0 * 64 + cin) * 9 + 3;
        const float* wk1 = w9 + (1 * 64 + cin) * 9 + 3;
        const float* wk2 = w9 + (2 * 64 + cin) * 9 + 3;
        acc0 += vm * wk0[0] + v0 * wk0[1] + vp * wk0[2];
        acc1 += vm * wk1[0] + v0 * wk1[1] + vp * wk1[2];
        acc2 += vm * wk2[0] + v0 * wk2[1] + vp * wk2[2];
    }
    float v;
    v = LEAKY(acc0);
    preds[i * 768 + 0 * 256 + wcol] = v;
    ebuf[0 * 31 * 256 + (15 + i) * 256 + wcol] = x[0 * 31 * 256 + (15 + i) * 256 + wcol] - v;
    v = LEAKY(acc1);
    preds[i * 768 + 1 * 256 + wcol] = v;
    ebuf[1 * 31 * 256 + (15 + i) * 256 + wcol] = x[1 * 31 * 256 + (15 + i) * 256 + wcol] - v;
    v = LEAKY(acc2);
    preds[i * 768 + 2 * 256 + wcol] = v;
    ebuf[2 * 31 * 256 + (15 + i) * 256 + wcol] = x[2 * 31 * 256 + (15 + i) * 256 + wcol] - v;
}

__global__ __launch_bounds__(256, 2) void fusedk(Params p)
{
    const int wg = blockIdx.x;
    unsigned* cnt = p.bar;
    unsigned* gen = p.bar + 64;

    for (int i = 0; i < 16; ++i) {
        convL(p.ebuf, 31 * 256, i, 15, 0,
              p.w1x, p.b1x, p.w1e, p.b1e, p.tA, 64 * 15 * 256, 15, 3, 1, 2, wg);
        gridbar(cnt, gen);
        convL(p.tA, 15 * 256, 0, 15, 64 * 15 * 256,
              p.w2x, p.b2x, p.w2e, p.b2e, p.tB, 64 * 13 * 256, 13, 64, 0, 2, wg);
        gridbar(cnt, gen);
        convL(p.tB, 13 * 256, 0, 13, 64 * 13 * 256,
              p.w3x, p.b3x, p.w3e, p.b3e, p.tA, 64 * 11 * 256, 11, 64, 0, 2, wg);
        gridbar(cnt, gen);
        convL(p.tA, 11 * 256, 0, 11, 64 * 11 * 256,
              p.w4x, p.b4x, p.w4e, p.b4e, p.tB, 64 * 9 * 256, 9, 64, 0, 2, wg);
        gridbar(cnt, gen);
        mm88d(p.tB, p.p0, wg);
        gridbar(cnt, gen);
        convL(p.p0, 9 * 256, 0, 9, 0,
              p.w5, p.b5, p.w5, p.b5, p.p1, 0, 7, 64, 0, 1, wg);
        gridbar(cnt, gen);
        convL(p.p1, 7 * 256, 0, 7, 0,
              p.w6, p.b6, p.w6, p.b6, p.p0, 0, 5, 64, 0, 1, wg);
        gridbar(cnt, gen);
        convL(p.p0, 5 * 256, 0, 5, 0,
              p.w7, p.b7, p.w7, p.b7, p.p1, 0, 3, 64, 0, 1, wg);
        gridbar(cnt, gen);
        convL(p.p1, 3 * 256, 0, 3, 0,
              p.w8, p.b8, p.w8, p.b8, p.p0, 0, 1, 64, 0, 1, wg);
        gridbar(cnt, gen);
        if (wg == 0) conv9upd(p.p0, p.w9, p.b9, p.x, p.ebuf, p.preds, i);
        gridbar(cnt, gen);
    }

    // finalize: d_out = [pred (3,16,256) | truth (3,16,256)]
    const int idx = wg * 256 + threadIdx.x;
    if (idx < 24576) {
        if (idx < 12288) {
            const int c = idx >> 12;
            const int t = (idx >> 8) & 15;
            const int w = idx & 255;
            p.out[idx] = p.preds[t * 768 + c * 256 + w];
        } else {
            const int j = idx - 12288;
            const int c = j >> 12;
            const int t = (j >> 8) & 15;
            const int w = j & 255;
            p.out[idx] = p.ebuf[c * 31 * 256 + (15 + t) * 256 + w];
        }
    }
}

extern "C" void kernel_launch(void* const* d_in, const int* in_sizes, int n_in,
                              void* d_out, int out_size, void* d_ws, size_t ws_size,
                              hipStream_t stream)
{
    Params p;
    p.x   = (const float*)d_in[0];
    p.w1x = (const float*)d_in[1];  p.b1x = (const float*)d_in[2];
    p.w2x = (const float*)d_in[3];  p.b2x = (const float*)d_in[4];
    p.w3x = (const float*)d_in[5];  p.b3x = (const float*)d_in[6];
    p.w4x = (const float*)d_in[7];  p.b4x = (const float*)d_in[8];
    p.w1e = (const float*)d_in[9];  p.b1e = (const float*)d_in[10];
    p.w2e = (const float*)d_in[11]; p.b2e = (const float*)d_in[12];
    p.w3e = (const float*)d_in[13]; p.b3e = (const float*)d_in[14];
    p.w4e = (const float*)d_in[15]; p.b4e = (const float*)d_in[16];
    p.w5  = (const float*)d_in[17]; p.b5  = (const float*)d_in[18];
    p.w6  = (const float*)d_in[19]; p.b6  = (const float*)d_in[20];
    p.w7  = (const float*)d_in[21]; p.b7  = (const float*)d_in[22];
    p.w8  = (const float*)d_in[23]; p.b8  = (const float*)d_in[24];
    p.w9  = (const float*)d_in[25]; p.b9  = (const float*)d_in[26];

    float* ws = (float*)d_ws;
    p.ebuf  = ws;                    // 3*31*256    = 23808
    p.tA    = p.ebuf + 23808;        // 2*64*15*256 = 491520
    p.tB    = p.tA + 491520;         // 2*64*15*256 = 491520
    p.p0    = p.tB + 491520;         // 64*9*256    = 147456
    p.p1    = p.p0 + 147456;         // 64*9*256    = 147456
    p.preds = p.p1 + 147456;         // 16*3*256    = 12288
    p.bar   = (unsigned*)(p.preds + 12288);  // 2 cache lines
    p.out   = (float*)d_out;

    hipMemsetAsync(p.bar, 0, 128 * sizeof(unsigned), stream);
    hipMemcpyAsync(p.ebuf, p.x, 23808 * sizeof(float), hipMemcpyDeviceToDevice, stream);

    fusedk<<<NWG, 256, 0, stream>>>(p);
}

// Round 3
// 4692.123 us; speedup vs baseline: 4.8772x; 4.8772x over previous
//
#include <hip/hip_runtime.h>

#define LEAKY(v) ((v) >= 0.f ? (v) : 0.01f * (v))

// ---------------- Layer 1 (CIN=3, PH=1, dual tower) ----------------
// grid (1, 15, 32), block 256. blockIdx.z = z*16 + cout_group(4 couts).
__global__ void conv3(const float* __restrict__ in, int inRow0,
                      const float* __restrict__ w0, const float* __restrict__ b0,
                      const float* __restrict__ w1, const float* __restrict__ b1,
                      float* __restrict__ out, int outZS)
{
    const int wcol = threadIdx.x;
    const int h  = blockIdx.y;        // 0..14
    const int cg = blockIdx.z & 15;
    const int z  = blockIdx.z >> 4;
    const float* W  = (z ? w1 : w0) + cg * 4 * 27;
    const float* Bv = z ? b1 : b0;

    float acc[4];
    #pragma unroll
    for (int j = 0; j < 4; ++j) acc[j] = Bv[cg * 4 + j];

    #pragma unroll
    for (int kh = 0; kh < 3; ++kh) {
        const int r = h - 1 + kh;
        const bool valid = (r >= 0 && r < 15);          // slice zero-pad
        const float msk = valid ? 1.f : 0.f;
        const float* rr = in + (inRow0 + (valid ? r : 0)) * 256;
        #pragma unroll
        for (int c = 0; c < 3; ++c) {
            const float* rc = rr + c * 31 * 256;        // ebuf channel stride
            float vm = (wcol > 0)   ? rc[wcol - 1] : 0.f;
            float v0 = rc[wcol];
            float vp = (wcol < 255) ? rc[wcol + 1] : 0.f;
            vm *= msk; v0 *= msk; vp *= msk;
            #pragma unroll
            for (int j = 0; j < 4; ++j) {
                const float* wj = W + j * 27 + c * 9 + kh * 3;
                acc[j] += vm * wj[0] + v0 * wj[1] + vp * wj[2];
            }
        }
    }
    float* o = out + (size_t)z * outZS;
    #pragma unroll
    for (int j = 0; j < 4; ++j)
        o[(cg * 4 + j) * 15 * 256 + h * 256 + wcol] = LEAKY(acc[j]);
}

// ---------------- CIN=64, PH=0 conv, manual depth-2 pipeline ----------------
// grid (1, Hout, 16*NZ), block 256. Each thread: 1 column, 4 couts, 1 row.
// Reads input rows h..h+2 (always valid: Hin = Hout + 2).
__global__ void conv64(const float* __restrict__ in, int inChS, int inZS,
                       const float* __restrict__ w0, const float* __restrict__ b0,
                       const float* __restrict__ w1, const float* __restrict__ b1,
                       float* __restrict__ out, int outZS, int Hout)
{
    const int wcol = threadIdx.x;
    const int h  = blockIdx.y;
    const int cg = blockIdx.z & 15;
    const int z  = blockIdx.z >> 4;
    const float* W  = (z ? w1 : w0) + cg * 4 * 576;     // 64*9 = 576 per cout
    const float* Bv = z ? b1 : b0;
    const float* ib = in + (size_t)z * inZS + h * 256;  // + cin*inChS + kh*256
    float* o = out + (size_t)z * outZS + h * 256;

    float acc[4];
    #pragma unroll
    for (int j = 0; j < 4; ++j) acc[j] = Bv[cg * 4 + j];

#define LD9(c, buf) do {                                              \
        const float* r_ = ib + (c) * inChS;                           \
        _Pragma("unroll")                                             \
        for (int kh_ = 0; kh_ < 3; ++kh_) {                           \
            const float* rr_ = r_ + kh_ * 256;                        \
            buf[kh_ * 3 + 0] = (wcol > 0)   ? rr_[wcol - 1] : 0.f;    \
            buf[kh_ * 3 + 1] = rr_[wcol];                             \
            buf[kh_ * 3 + 2] = (wcol < 255) ? rr_[wcol + 1] : 0.f;    \
        }                                                             \
    } while (0)

    float A[9], B[9], C[9], D[9];
    LD9(0, A);
    LD9(1, B);
    for (int cin = 0; cin < 64; cin += 2) {
        if (cin + 2 < 64) { LD9(cin + 2, C); LD9(cin + 3, D); }
        #pragma unroll
        for (int j = 0; j < 4; ++j) {
            const float* wj = W + j * 576 + cin * 9;
            #pragma unroll
            for (int t = 0; t < 9; ++t) acc[j] += A[t] * wj[t];
            #pragma unroll
            for (int t = 0; t < 9; ++t) acc[j] += B[t] * wj[t + 9];
        }
        #pragma unroll
        for (int t = 0; t < 9; ++t) { A[t] = C[t]; B[t] = D[t]; }
    }
#undef LD9

    const int ohw = Hout * 256;
    #pragma unroll
    for (int j = 0; j < 4; ++j)
        o[(cg * 4 + j) * ohw] = LEAKY(acc[j]);
    // note: o already offset by h*256; index (cg*4+j)*ohw + wcol handled below
}

// conv64 store fix helper (kept inline above would mis-index); use a wrapper:
// (We re-declare conv64 with correct store — see conv64b below.)

__global__ void conv64b(const float* __restrict__ in, int inChS, int inZS,
                        const float* __restrict__ w0, const float* __restrict__ b0,
                        const float* __restrict__ w1, const float* __restrict__ b1,
                        float* __restrict__ out, int outZS, int Hout)
{
    const int wcol = threadIdx.x;
    const int h  = blockIdx.y;
    const int cg = blockIdx.z & 15;
    const int z  = blockIdx.z >> 4;
    const float* W  = (z ? w1 : w0) + cg * 4 * 576;
    const float* Bv = z ? b1 : b0;
    const float* ib = in + (size_t)z * inZS + h * 256;
    float* o = out + (size_t)z * outZS;

    float acc[4];
    #pragma unroll
    for (int j = 0; j < 4; ++j) acc[j] = Bv[cg * 4 + j];

#define LD9(c, buf) do {                                              \
        const float* r_ = ib + (c) * inChS;                           \
        _Pragma("unroll")                                             \
        for (int kh_ = 0; kh_ < 3; ++kh_) {                           \
            const float* rr_ = r_ + kh_ * 256;                        \
            buf[kh_ * 3 + 0] = (wcol > 0)   ? rr_[wcol - 1] : 0.f;    \
            buf[kh_ * 3 + 1] = rr_[wcol];                             \
            buf[kh_ * 3 + 2] = (wcol < 255) ? rr_[wcol + 1] : 0.f;    \
        }                                                             \
    } while (0)

    float A[9], B[9], C[9], D[9];
    LD9(0, A);
    LD9(1, B);
    for (int cin = 0; cin < 64; cin += 2) {
        if (cin + 2 < 64) { LD9(cin + 2, C); LD9(cin + 3, D); }
        #pragma unroll
        for (int j = 0; j < 4; ++j) {
            const float* wj = W + j * 576 + cin * 9;
            #pragma unroll
            for (int t = 0; t < 9; ++t) acc[j] += A[t] * wj[t];
            #pragma unroll
            for (int t = 0; t < 9; ++t) acc[j] += B[t] * wj[t + 9];
        }
        #pragma unroll
        for (int t = 0; t < 9; ++t) { A[t] = C[t]; B[t] = D[t]; }
    }
#undef LD9

    const int ohw = Hout * 256;
    #pragma unroll
    for (int j = 0; j < 4; ++j)
        o[(cg * 4 + j) * ohw + h * 256 + wcol] = LEAKY(acc[j]);
}

// ---------------- Per-pixel 8x8 @ 8x8 ----------------
__global__ void mm88(const float* __restrict__ tw, float* __restrict__ p0)
{
    const int idx = blockIdx.x * 256 + threadIdx.x;   // pixel in 9*256
    const float* s = tw;
    const float* e = tw + 64 * 9 * 256;
    float sv[64];
    #pragma unroll
    for (int c = 0; c < 64; ++c) sv[c] = s[c * 9 * 256 + idx];
    #pragma unroll
    for (int i = 0; i < 8; ++i) {
        float ev[8];
        #pragma unroll
        for (int j = 0; j < 8; ++j) ev[j] = e[(i * 8 + j) * 9 * 256 + idx];
        #pragma unroll
        for (int k = 0; k < 8; ++k) {
            float acc = 0.f;
            #pragma unroll
            for (int j = 0; j < 8; ++j) acc += ev[j] * sv[j * 8 + k];
            p0[(i * 8 + k) * 9 * 256 + idx] = acc;
        }
    }
}

// ---------------- conv9 (64->3, kh=1 taps only) + recurrence update ----------------
// block (256,4): threadIdx.y owns 16 cins; LDS reduce; y==0 finalizes.
__global__ void conv9up(const float* __restrict__ pin, const float* __restrict__ w9,
                        const float* __restrict__ b9, const float* __restrict__ x,
                        float* __restrict__ ebuf, float* __restrict__ preds, int i)
{
    const int wcol = threadIdx.x;
    const int yq   = threadIdx.y;       // 0..3
    const int c0   = yq * 16;
    float a0 = 0.f, a1 = 0.f, a2 = 0.f;

#define LD3(c, buf) do {                                              \
        const float* r_ = pin + (c0 + (c)) * 256;                     \
        buf[0] = (wcol > 0)   ? r_[wcol - 1] : 0.f;                   \
        buf[1] = r_[wcol];                                            \
        buf[2] = (wcol < 255) ? r_[wcol + 1] : 0.f;                   \
    } while (0)

    float A[3], B[3], C[3], D[3];
    LD3(0, A);
    LD3(1, B);
    for (int c = 0; c < 16; c += 2) {
        if (c + 2 < 16) { LD3(c + 2, C); LD3(c + 3, D); }
        const int cin = c0 + c;
        #pragma unroll
        for (int j = 0; j < 3; ++j) {
            const float* wk = w9 + (j * 64 + cin) * 9 + 3;   // kh=1
            float t = A[0] * wk[0] + A[1] * wk[1] + A[2] * wk[2]
                    + B[0] * wk[9] + B[1] * wk[10] + B[2] * wk[11];
            if (j == 0) a0 += t; else if (j == 1) a1 += t; else a2 += t;
        }
        #pragma unroll
        for (int t = 0; t < 3; ++t) { A[t] = C[t]; B[t] = D[t]; }
    }
#undef LD3

    __shared__ float red[4][3][256];
    red[yq][0][wcol] = a0;
    red[yq][1][wcol] = a1;
    red[yq][2][wcol] = a2;
    __syncthreads();

    if (yq == 0) {
        #pragma unroll
        for (int j = 0; j < 3; ++j) {
            float v = b9[j] + red[0][j][wcol] + red[1][j][wcol]
                            + red[2][j][wcol] + red[3][j][wcol];
            v = LEAKY(v);
            preds[i * 768 + j * 256 + wcol] = v;
            ebuf[j * 31 * 256 + (15 + i) * 256 + wcol] =
                x[j * 31 * 256 + (15 + i) * 256 + wcol] - v;
        }
    }
}

// ---------------- finalize ----------------
__global__ void finalize(const float* __restrict__ preds, const float* __restrict__ ebuf,
                         float* __restrict__ o)
{
    const int idx = blockIdx.x * 256 + threadIdx.x;
    if (idx >= 24576) return;
    if (idx < 12288) {
        const int c = idx >> 12;
        const int t = (idx >> 8) & 15;
        const int w = idx & 255;
        o[idx] = preds[t * 768 + c * 256 + w];
    } else {
        const int j = idx - 12288;
        const int c = j >> 12;
        const int t = (j >> 8) & 15;
        const int w = j & 255;
        o[idx] = ebuf[c * 31 * 256 + (15 + t) * 256 + w];
    }
}

extern "C" void kernel_launch(void* const* d_in, const int* in_sizes, int n_in,
                              void* d_out, int out_size, void* d_ws, size_t ws_size,
                              hipStream_t stream)
{
    const float* x   = (const float*)d_in[0];
    const float* w1x = (const float*)d_in[1];  const float* b1x = (const float*)d_in[2];
    const float* w2x = (const float*)d_in[3];  const float* b2x = (const float*)d_in[4];
    const float* w3x = (const float*)d_in[5];  const float* b3x = (const float*)d_in[6];
    const float* w4x = (const float*)d_in[7];  const float* b4x = (const float*)d_in[8];
    const float* w1e = (const float*)d_in[9];  const float* b1e = (const float*)d_in[10];
    const float* w2e = (const float*)d_in[11]; const float* b2e = (const float*)d_in[12];
    const float* w3e = (const float*)d_in[13]; const float* b3e = (const float*)d_in[14];
    const float* w4e = (const float*)d_in[15]; const float* b4e = (const float*)d_in[16];
    const float* w5  = (const float*)d_in[17]; const float* b5  = (const float*)d_in[18];
    const float* w6  = (const float*)d_in[19]; const float* b6  = (const float*)d_in[20];
    const float* w7  = (const float*)d_in[21]; const float* b7  = (const float*)d_in[22];
    const float* w8  = (const float*)d_in[23]; const float* b8  = (const float*)d_in[24];
    const float* w9  = (const float*)d_in[25]; const float* b9  = (const float*)d_in[26];

    float* ws    = (float*)d_ws;
    float* ebuf  = ws;                   // 3*31*256    = 23808
    float* tA    = ebuf + 23808;         // 2*64*15*256 = 491520
    float* tB    = tA + 491520;          // 2*64*15*256 = 491520
    float* p0    = tB + 491520;          // 64*9*256    = 147456
    float* p1    = p0 + 147456;          // 64*9*256    = 147456
    float* preds = p1 + 147456;          // 16*3*256    = 12288

    hipMemcpyAsync(ebuf, x, 23808 * sizeof(float), hipMemcpyDeviceToDevice, stream);

    for (int i = 0; i < 16; ++i) {
        conv3<<<dim3(1, 15, 32), 256, 0, stream>>>(ebuf, i, w1x, b1x, w1e, b1e,
                                                   tA, 64 * 15 * 256);
        conv64b<<<dim3(1, 13, 32), 256, 0, stream>>>(tA, 15 * 256, 64 * 15 * 256,
                                                     w2x, b2x, w2e, b2e,
                                                     tB, 64 * 13 * 256, 13);
        conv64b<<<dim3(1, 11, 32), 256, 0, stream>>>(tB, 13 * 256, 64 * 13 * 256,
                                                     w3x, b3x, w3e, b3e,
                                                     tA, 64 * 11 * 256, 11);
        conv64b<<<dim3(1, 9, 32), 256, 0, stream>>>(tA, 11 * 256, 64 * 11 * 256,
                                                    w4x, b4x, w4e, b4e,
                                                    tB, 64 * 9 * 256, 9);
        mm88<<<9, 256, 0, stream>>>(tB, p0);
        conv64b<<<dim3(1, 7, 16), 256, 0, stream>>>(p0, 9 * 256, 0,
                                                    w5, b5, w5, b5, p1, 0, 7);
        conv64b<<<dim3(1, 5, 16), 256, 0, stream>>>(p1, 7 * 256, 0,
                                                    w6, b6, w6, b6, p0, 0, 5);
        conv64b<<<dim3(1, 3, 16), 256, 0, stream>>>(p0, 5 * 256, 0,
                                                    w7, b7, w7, b7, p1, 0, 3);
        conv64b<<<dim3(1, 1, 16), 256, 0, stream>>>(p1, 3 * 256, 0,
                                                    w8, b8, w8, b8, p0, 0, 1);
        conv9up<<<1, dim3(256, 4), 0, stream>>>(p0, w9, b9, x, ebuf, preds, i);
    }

    finalize<<<96, 256, 0, stream>>>(preds, ebuf, (float*)d_out);
}